// Round 9
// baseline (211.699 us; speedup 1.0000x reference)
//
#include <hip/hip_runtime.h>

// Reinsertion: B=32, G=512, D=128, H=4, KD=32. Output (B,G,G) fp32.
//
// R9: latency attack. mlp_pairs loop body now carries 4 independent
// MFMA chains (2 g1 rows x 2 g2 chunks, 8 iterations) and
// __launch_bounds__(256,4) lifts the VGPR cap to 128 so the chains and
// hoisted ds_reads can be live concurrently (R8: VGPR=72 serialized the
// unrolled iterations -> VALUBusy 65%, latency-bound at 48 us).

#define B 32
#define G 512
#define D 128
#define NH 4
#define KD 32
#define NORMF 0.17677669529663687f  // 1/sqrt(32)

// ws: fp16 P/Q only (half-indices)
#define WS_P16H 131072
#define WS_Q16H 655360

typedef float v16f __attribute__((ext_vector_type(16)));
typedef float f2v __attribute__((ext_vector_type(2)));
typedef _Float16 v8h __attribute__((ext_vector_type(8)));
typedef _Float16 h2v __attribute__((ext_vector_type(2)));

struct HQ { h2v h[4]; };   // 8 halves = 4 VGPRs
struct F2x8 { f2v v[8]; }; // 16 floats as 8 packed pairs

__device__ __forceinline__ v8h relu_add(const HQ& p, const HQ& q) {
  const h2v z = {(_Float16)0.0f, (_Float16)0.0f};
  HQ r;
#pragma unroll
  for (int i = 0; i < 4; ++i)
    r.h[i] = __builtin_elementwise_max(p.h[i] + q.h[i], z);
  return __builtin_bit_cast(v8h, r);
}

// ---------------- Stage 0+1 fused: A-tables (LDS) + P/Q vectors ----------------
__global__ __launch_bounds__(256) void stage01(
    const float* __restrict__ h, const int* __restrict__ pp,
    const int* __restrict__ pd, const int* __restrict__ rec,
    const float* __restrict__ Wq1, const float* __restrict__ Wk1,
    const float* __restrict__ Wq2, const float* __restrict__ Wk2,
    const float* __restrict__ fc1_w, const float* __restrict__ fc1_b,
    float* __restrict__ ws) {
  const int bx = blockIdx.x;
  const int b = bx >> 3, g0 = (bx & 7) * 64;
  const int t = threadIdx.x;

  __shared__ float hp[D], hd[D];
  __shared__ float qq[4][NH * KD];   // q1p,q2p,q1d,q2d
  __shared__ float sA[4][NH][D];     // Apq,Apo,Adp,Ado
  __shared__ float sc[64][17];
  __shared__ float sout[64][33];

  if (t < 128) {
    hp[t] = h[((size_t)b * G + pp[b]) * D + t];
  } else {
    const int u = t - 128;
    hd[u] = h[((size_t)b * G + pd[b]) * D + u];
  }
  __syncthreads();

  if (t < 128) {  // t -> (head hh, key k); dot over d
    const int hh = t >> 5, k = t & 31;
    const float* wq1 = Wq1 + hh * D * KD + k;
    const float* wq2 = Wq2 + hh * D * KD + k;
    float s1p = 0.f, s2p = 0.f, s1d = 0.f, s2d = 0.f;
    for (int d = 0; d < D; ++d) {
      const float w1 = wq1[d * KD], w2 = wq2[d * KD];
      const float xp = hp[d], xd = hd[d];
      s1p = fmaf(xp, w1, s1p);
      s2p = fmaf(xp, w2, s2p);
      s1d = fmaf(xd, w1, s1d);
      s2d = fmaf(xd, w2, s2d);
    }
    qq[0][t] = s1p; qq[1][t] = s2p; qq[2][t] = s1d; qq[3][t] = s2d;
  }
  __syncthreads();

  {  // A[table][hh][d]; thread t: d = t&127, two heads
    const int d = t & 127;
    const int h0 = (t >> 7) * 2;
#pragma unroll
    for (int hh = h0; hh < h0 + 2; ++hh) {
      const float* wk1 = Wk1 + hh * D * KD + d * KD;
      const float* wk2 = Wk2 + hh * D * KD + d * KD;
      float apq = 0.f, apo = 0.f, adp = 0.f, ado = 0.f;
#pragma unroll
      for (int k = 0; k < KD; ++k) {
        const float w1 = wk1[k], w2 = wk2[k];
        apq = fmaf(qq[0][hh * 32 + k], w1, apq);
        adp = fmaf(qq[2][hh * 32 + k], w1, adp);
        apo = fmaf(qq[1][hh * 32 + k], w2, apo);
        ado = fmaf(qq[3][hh * 32 + k], w2, ado);
      }
      sA[0][hh][d] = NORMF * apq;
      sA[1][hh][d] = NORMF * apo;
      sA[2][hh][d] = NORMF * adp;
      sA[3][hh][d] = NORMF * ado;
    }
  }
  __syncthreads();

  // Phase B: compat dots + fc1 decomposition
  const int gl = t & 63;
  const int hh = __builtin_amdgcn_readfirstlane(t >> 6);  // wave id == head
  const int g = g0 + gl;
  const float4* hg4 = (const float4*)(h + ((size_t)b * G + g) * D);
  const float4* hn4 = (const float4*)(h + ((size_t)b * G + rec[b * G + g]) * D);

  float cpp = 0.f, cpo = 0.f, cdp = 0.f, cdo = 0.f;
#pragma unroll 4
  for (int d4 = 0; d4 < 32; ++d4) {
    const float4 x = hg4[d4], y = hn4[d4];
    const float4 a1 = *(const float4*)&sA[0][hh][4 * d4];
    const float4 a2 = *(const float4*)&sA[1][hh][4 * d4];
    const float4 a3 = *(const float4*)&sA[2][hh][4 * d4];
    const float4 a4 = *(const float4*)&sA[3][hh][4 * d4];
    cpp = fmaf(x.x, a1.x, fmaf(x.y, a1.y, fmaf(x.z, a1.z, fmaf(x.w, a1.w, cpp))));
    cpo = fmaf(y.x, a2.x, fmaf(y.y, a2.y, fmaf(y.z, a2.z, fmaf(y.w, a2.w, cpo))));
    cdp = fmaf(x.x, a3.x, fmaf(x.y, a3.y, fmaf(x.z, a3.z, fmaf(x.w, a3.w, cdp))));
    cdo = fmaf(y.x, a4.x, fmaf(y.y, a4.y, fmaf(y.z, a4.z, fmaf(y.w, a4.w, cdo))));
  }
  sc[gl][hh] = cpp; sc[gl][4 + hh] = cpo; sc[gl][8 + hh] = cdp; sc[gl][12 + hh] = cdo;
  __syncthreads();

  float u[16];
#pragma unroll
  for (int i = 0; i < 16; ++i) u[i] = sc[gl][i];

  float pv[8], qv[8];
#pragma unroll
  for (int jj = 0; jj < 8; ++jj) {
    const int j = hh * 8 + jj;  // wave-uniform -> s_load weights
    float p = 0.f, q = fc1_b[j];
#pragma unroll
    for (int i = 0; i < 8; ++i) {
      p = fmaf(u[i], fc1_w[i * 32 + j], p);
      q = fmaf(u[8 + i], fc1_w[(8 + i) * 32 + j], q);
    }
    pv[jj] = p; qv[jj] = q;
  }

  // pack to fp16, transpose via LDS, coalesced uint stores
#pragma unroll
  for (int jj = 0; jj < 8; ++jj) sout[gl][hh * 8 + jj] = pv[jj];
  __syncthreads();
  {
    unsigned* dst = (unsigned*)((unsigned short*)ws + WS_P16H) +
                    ((size_t)b * G + g0) * 16;
#pragma unroll
    for (int i = t; i < 1024; i += 256) {
      const int row = i >> 4, c0 = (2 * i) & 31;
      __fp16 __attribute__((ext_vector_type(2))) pk =
          __builtin_amdgcn_cvt_pkrtz(sout[row][c0], sout[row][c0 + 1]);
      dst[i] = *(const unsigned*)&pk;
    }
  }
  __syncthreads();
#pragma unroll
  for (int jj = 0; jj < 8; ++jj) sout[gl][hh * 8 + jj] = qv[jj];
  __syncthreads();
  {
    unsigned* dst = (unsigned*)((unsigned short*)ws + WS_Q16H) +
                    ((size_t)b * G + g0) * 16;
#pragma unroll
    for (int i = t; i < 1024; i += 256) {
      const int row = i >> 4, c0 = (2 * i) & 31;
      __fp16 __attribute__((ext_vector_type(2))) pk =
          __builtin_amdgcn_cvt_pkrtz(sout[row][c0], sout[row][c0 + 1]);
      dst[i] = *(const unsigned*)&pk;
    }
  }
}

// ---------------- Stage 2: per-pair MLP via 32x32x16 f16 MFMA ----------------
// Grid (2,32,32); block 256 = 4 waves; wave w owns chunks {2w,2w+1} of 32 g2.
// 8 iterations, each covering 2 g1 rows x 2 chunks = 4 independent MFMA
// chains + 4 independent epilogues (ILP for latency hiding).
// __launch_bounds__(256,4): VGPR cap 128 so the chains stay live.
__global__ __launch_bounds__(256, 4) void mlp_pairs(
    const float* __restrict__ ws,
    const float* __restrict__ fc2_w, const float* __restrict__ fc2_b,
    const float* __restrict__ fc3_w, const float* __restrict__ fc3_b,
    float* __restrict__ out) {
  const int b = blockIdx.z;
  const int g1_0 = blockIdx.y * 16;
  const int g2_0 = blockIdx.x * 256;
  const int t = threadIdx.x;
  const int w = t >> 6, l = t & 63;
  const int col = l & 31;   // pair within chunk
  const int half = l >> 5;  // k-subrange / n-subset selector
  const int kb = half * 8;

  __shared__ __align__(16) unsigned short sPh[16 * 32];  // 1 KB P tile
  {
    const unsigned* Psrc = (const unsigned*)((const unsigned short*)ws + WS_P16H) +
                           ((size_t)b * G + g1_0) * 16;
    ((unsigned*)sPh)[t] = Psrc[t];
  }

  // A-frags: W2t[n=col][k = kb+j] (f16 RTN); k-halves [0,16) / [16,32)
  v8h A0, A1;
#pragma unroll
  for (int j = 0; j < 8; ++j) {
    A0[j] = (_Float16)fc2_w[(kb + j) * 32 + col];
    A1[j] = (_Float16)fc2_w[(16 + kb + j) * 32 + col];
  }
  // Bias as C-seed; fc3 weights as packed pairs (n-mapped)
  v16f biasC;
  F2x8 w3p;
#pragma unroll
  for (int r = 0; r < 16; ++r) {
    const int n = (r & 3) + 8 * (r >> 2) + 4 * half;
    biasC[r] = fc2_b[n];
    ((float*)&w3p)[r] = fc3_w[n];
  }
  const float b3 = fc3_b[0];

  // Q fragments (g1-invariant, fp16) for both chunks
  HQ qlo[2], qhi[2];
#pragma unroll
  for (int c = 0; c < 2; ++c) {
    const unsigned short* qp = (const unsigned short*)ws + WS_Q16H +
        ((size_t)b * G + g2_0 + (2 * w + c) * 32 + col) * 32;
    qlo[c] = __builtin_bit_cast(HQ, *(const uint4*)(qp + kb));
    qhi[c] = __builtin_bit_cast(HQ, *(const uint4*)(qp + 16 + kb));
  }
  __syncthreads();

  const f2v z2 = {0.f, 0.f};
  float* op = out + (((size_t)b * G + g1_0) * G) + g2_0 + w * 64 + half * 32 + col;
#pragma unroll
  for (int i = 0; i < 8; ++i) {
    const int ra = 2 * i, rb = 2 * i + 1;
    const HQ palo = __builtin_bit_cast(HQ, *(const uint4*)(sPh + ra * 32 + kb));
    const HQ pahi = __builtin_bit_cast(HQ, *(const uint4*)(sPh + ra * 32 + 16 + kb));
    const HQ pblo = __builtin_bit_cast(HQ, *(const uint4*)(sPh + rb * 32 + kb));
    const HQ pbhi = __builtin_bit_cast(HQ, *(const uint4*)(sPh + rb * 32 + 16 + kb));

    // 8 B-frags, 8 MFMAs: 4 independent chains
    const v8h Ba0lo = relu_add(palo, qlo[0]);
    const v8h Ba0hi = relu_add(pahi, qhi[0]);
    const v8h Ba1lo = relu_add(palo, qlo[1]);
    const v8h Ba1hi = relu_add(pahi, qhi[1]);
    const v8h Bb0lo = relu_add(pblo, qlo[0]);
    const v8h Bb0hi = relu_add(pbhi, qhi[0]);
    const v8h Bb1lo = relu_add(pblo, qlo[1]);
    const v8h Bb1hi = relu_add(pbhi, qhi[1]);

    v16f aa0 = __builtin_amdgcn_mfma_f32_32x32x16_f16(A0, Ba0lo, biasC, 0, 0, 0);
    v16f aa1 = __builtin_amdgcn_mfma_f32_32x32x16_f16(A0, Ba1lo, biasC, 0, 0, 0);
    v16f ab0 = __builtin_amdgcn_mfma_f32_32x32x16_f16(A0, Bb0lo, biasC, 0, 0, 0);
    v16f ab1 = __builtin_amdgcn_mfma_f32_32x32x16_f16(A0, Bb1lo, biasC, 0, 0, 0);
    aa0 = __builtin_amdgcn_mfma_f32_32x32x16_f16(A1, Ba0hi, aa0, 0, 0, 0);
    aa1 = __builtin_amdgcn_mfma_f32_32x32x16_f16(A1, Ba1hi, aa1, 0, 0, 0);
    ab0 = __builtin_amdgcn_mfma_f32_32x32x16_f16(A1, Bb0hi, ab0, 0, 0, 0);
    ab1 = __builtin_amdgcn_mfma_f32_32x32x16_f16(A1, Bb1hi, ab1, 0, 0, 0);

    // 4 packed-fp32 epilogues
    const F2x8 fa0 = __builtin_bit_cast(F2x8, aa0);
    const F2x8 fa1 = __builtin_bit_cast(F2x8, aa1);
    const F2x8 fb0 = __builtin_bit_cast(F2x8, ab0);
    const F2x8 fb1 = __builtin_bit_cast(F2x8, ab1);
    f2v ea0 = z2, ea1 = z2, eb0 = z2, eb1 = z2;
#pragma unroll
    for (int k = 0; k < 8; ++k) {
      ea0 = __builtin_elementwise_max(fa0.v[k], z2) * w3p.v[k] + ea0;
      ea1 = __builtin_elementwise_max(fa1.v[k], z2) * w3p.v[k] + ea1;
      eb0 = __builtin_elementwise_max(fb0.v[k], z2) * w3p.v[k] + eb0;
      eb1 = __builtin_elementwise_max(fb1.v[k], z2) * w3p.v[k] + eb1;
    }
    const float sa0 = ea0[0] + ea0[1], sa1 = ea1[0] + ea1[1];
    const float sb0 = eb0[0] + eb0[1], sb1 = eb1[0] + eb1[1];

    // single-shuffle cross-half reduce per row (select-swap)
    float ya = half ? sa1 : sa0;
    float za = half ? sa0 : sa1;
    ya += __shfl_xor(za, 32);
    float yb = half ? sb1 : sb0;
    float zb = half ? sb0 : sb1;
    yb += __shfl_xor(zb, 32);

    op[(size_t)ra * G] = ya + b3;
    op[(size_t)rb * G] = yb + b3;
  }
}

extern "C" void kernel_launch(void* const* d_in, const int* in_sizes, int n_in,
                              void* d_out, int out_size, void* d_ws, size_t ws_size,
                              hipStream_t stream) {
  const float* h     = (const float*)d_in[0];
  const int*   pp    = (const int*)d_in[1];
  const int*   pd    = (const int*)d_in[2];
  const int*   rec   = (const int*)d_in[3];
  const float* Wq1   = (const float*)d_in[4];
  const float* Wk1   = (const float*)d_in[5];
  const float* Wq2   = (const float*)d_in[6];
  const float* Wk2   = (const float*)d_in[7];
  const float* fc1_w = (const float*)d_in[8];
  const float* fc1_b = (const float*)d_in[9];
  const float* fc2_w = (const float*)d_in[10];
  const float* fc2_b = (const float*)d_in[11];
  const float* fc3_w = (const float*)d_in[12];
  const float* fc3_b = (const float*)d_in[13];
  float* out = (float*)d_out;
  float* ws  = (float*)d_ws;

  stage01<<<dim3(256), dim3(256), 0, stream>>>(
      h, pp, pd, rec, Wq1, Wk1, Wq2, Wk2, fc1_w, fc1_b, ws);
  mlp_pairs<<<dim3(2, 32, 32), dim3(256), 0, stream>>>(
      ws, fc2_w, fc2_b, fc3_w, fc3_b, out);
}

// Round 10
// 144.253 us; speedup vs baseline: 1.4675x; 1.4675x over previous
//
#include <hip/hip_runtime.h>

// Reinsertion: B=32, G=512, D=128, H=4, KD=32. Output (B,G,G) fp32.
//
// R10 = R9's 4-independent-chain loop body (2 g1 rows x 2 g2 chunks per
// iteration) with __launch_bounds__(256,2): 256-VGPR budget fits the ~170-reg
// live set, eliminating R9's scratch spill (FETCH 251 MB -> ~3 MB) while
// keeping the ILP needed to break the latency-bound 47-us plateau of R6/R8.

#define B 32
#define G 512
#define D 128
#define NH 4
#define KD 32
#define NORMF 0.17677669529663687f  // 1/sqrt(32)

// ws: fp16 P/Q only (half-indices)
#define WS_P16H 131072
#define WS_Q16H 655360

typedef float v16f __attribute__((ext_vector_type(16)));
typedef float f2v __attribute__((ext_vector_type(2)));
typedef _Float16 v8h __attribute__((ext_vector_type(8)));
typedef _Float16 h2v __attribute__((ext_vector_type(2)));

struct HQ { h2v h[4]; };   // 8 halves = 4 VGPRs
struct F2x8 { f2v v[8]; }; // 16 floats as 8 packed pairs

__device__ __forceinline__ v8h relu_add(const HQ& p, const HQ& q) {
  const h2v z = {(_Float16)0.0f, (_Float16)0.0f};
  HQ r;
#pragma unroll
  for (int i = 0; i < 4; ++i)
    r.h[i] = __builtin_elementwise_max(p.h[i] + q.h[i], z);
  return __builtin_bit_cast(v8h, r);
}

// ---------------- Stage 0+1 fused: A-tables (LDS) + P/Q vectors ----------------
__global__ __launch_bounds__(256) void stage01(
    const float* __restrict__ h, const int* __restrict__ pp,
    const int* __restrict__ pd, const int* __restrict__ rec,
    const float* __restrict__ Wq1, const float* __restrict__ Wk1,
    const float* __restrict__ Wq2, const float* __restrict__ Wk2,
    const float* __restrict__ fc1_w, const float* __restrict__ fc1_b,
    float* __restrict__ ws) {
  const int bx = blockIdx.x;
  const int b = bx >> 3, g0 = (bx & 7) * 64;
  const int t = threadIdx.x;

  __shared__ float hp[D], hd[D];
  __shared__ float qq[4][NH * KD];   // q1p,q2p,q1d,q2d
  __shared__ float sA[4][NH][D];     // Apq,Apo,Adp,Ado
  __shared__ float sc[64][17];
  __shared__ float sout[64][33];

  if (t < 128) {
    hp[t] = h[((size_t)b * G + pp[b]) * D + t];
  } else {
    const int u = t - 128;
    hd[u] = h[((size_t)b * G + pd[b]) * D + u];
  }
  __syncthreads();

  if (t < 128) {  // t -> (head hh, key k); dot over d
    const int hh = t >> 5, k = t & 31;
    const float* wq1 = Wq1 + hh * D * KD + k;
    const float* wq2 = Wq2 + hh * D * KD + k;
    float s1p = 0.f, s2p = 0.f, s1d = 0.f, s2d = 0.f;
    for (int d = 0; d < D; ++d) {
      const float w1 = wq1[d * KD], w2 = wq2[d * KD];
      const float xp = hp[d], xd = hd[d];
      s1p = fmaf(xp, w1, s1p);
      s2p = fmaf(xp, w2, s2p);
      s1d = fmaf(xd, w1, s1d);
      s2d = fmaf(xd, w2, s2d);
    }
    qq[0][t] = s1p; qq[1][t] = s2p; qq[2][t] = s1d; qq[3][t] = s2d;
  }
  __syncthreads();

  {  // A[table][hh][d]; thread t: d = t&127, two heads
    const int d = t & 127;
    const int h0 = (t >> 7) * 2;
#pragma unroll
    for (int hh = h0; hh < h0 + 2; ++hh) {
      const float* wk1 = Wk1 + hh * D * KD + d * KD;
      const float* wk2 = Wk2 + hh * D * KD + d * KD;
      float apq = 0.f, apo = 0.f, adp = 0.f, ado = 0.f;
#pragma unroll
      for (int k = 0; k < KD; ++k) {
        const float w1 = wk1[k], w2 = wk2[k];
        apq = fmaf(qq[0][hh * 32 + k], w1, apq);
        adp = fmaf(qq[2][hh * 32 + k], w1, adp);
        apo = fmaf(qq[1][hh * 32 + k], w2, apo);
        ado = fmaf(qq[3][hh * 32 + k], w2, ado);
      }
      sA[0][hh][d] = NORMF * apq;
      sA[1][hh][d] = NORMF * apo;
      sA[2][hh][d] = NORMF * adp;
      sA[3][hh][d] = NORMF * ado;
    }
  }
  __syncthreads();

  // Phase B: compat dots + fc1 decomposition
  const int gl = t & 63;
  const int hh = __builtin_amdgcn_readfirstlane(t >> 6);  // wave id == head
  const int g = g0 + gl;
  const float4* hg4 = (const float4*)(h + ((size_t)b * G + g) * D);
  const float4* hn4 = (const float4*)(h + ((size_t)b * G + rec[b * G + g]) * D);

  float cpp = 0.f, cpo = 0.f, cdp = 0.f, cdo = 0.f;
#pragma unroll 4
  for (int d4 = 0; d4 < 32; ++d4) {
    const float4 x = hg4[d4], y = hn4[d4];
    const float4 a1 = *(const float4*)&sA[0][hh][4 * d4];
    const float4 a2 = *(const float4*)&sA[1][hh][4 * d4];
    const float4 a3 = *(const float4*)&sA[2][hh][4 * d4];
    const float4 a4 = *(const float4*)&sA[3][hh][4 * d4];
    cpp = fmaf(x.x, a1.x, fmaf(x.y, a1.y, fmaf(x.z, a1.z, fmaf(x.w, a1.w, cpp))));
    cpo = fmaf(y.x, a2.x, fmaf(y.y, a2.y, fmaf(y.z, a2.z, fmaf(y.w, a2.w, cpo))));
    cdp = fmaf(x.x, a3.x, fmaf(x.y, a3.y, fmaf(x.z, a3.z, fmaf(x.w, a3.w, cdp))));
    cdo = fmaf(y.x, a4.x, fmaf(y.y, a4.y, fmaf(y.z, a4.z, fmaf(y.w, a4.w, cdo))));
  }
  sc[gl][hh] = cpp; sc[gl][4 + hh] = cpo; sc[gl][8 + hh] = cdp; sc[gl][12 + hh] = cdo;
  __syncthreads();

  float u[16];
#pragma unroll
  for (int i = 0; i < 16; ++i) u[i] = sc[gl][i];

  float pv[8], qv[8];
#pragma unroll
  for (int jj = 0; jj < 8; ++jj) {
    const int j = hh * 8 + jj;  // wave-uniform -> s_load weights
    float p = 0.f, q = fc1_b[j];
#pragma unroll
    for (int i = 0; i < 8; ++i) {
      p = fmaf(u[i], fc1_w[i * 32 + j], p);
      q = fmaf(u[8 + i], fc1_w[(8 + i) * 32 + j], q);
    }
    pv[jj] = p; qv[jj] = q;
  }

  // pack to fp16, transpose via LDS, coalesced uint stores
#pragma unroll
  for (int jj = 0; jj < 8; ++jj) sout[gl][hh * 8 + jj] = pv[jj];
  __syncthreads();
  {
    unsigned* dst = (unsigned*)((unsigned short*)ws + WS_P16H) +
                    ((size_t)b * G + g0) * 16;
#pragma unroll
    for (int i = t; i < 1024; i += 256) {
      const int row = i >> 4, c0 = (2 * i) & 31;
      __fp16 __attribute__((ext_vector_type(2))) pk =
          __builtin_amdgcn_cvt_pkrtz(sout[row][c0], sout[row][c0 + 1]);
      dst[i] = *(const unsigned*)&pk;
    }
  }
  __syncthreads();
#pragma unroll
  for (int jj = 0; jj < 8; ++jj) sout[gl][hh * 8 + jj] = qv[jj];
  __syncthreads();
  {
    unsigned* dst = (unsigned*)((unsigned short*)ws + WS_Q16H) +
                    ((size_t)b * G + g0) * 16;
#pragma unroll
    for (int i = t; i < 1024; i += 256) {
      const int row = i >> 4, c0 = (2 * i) & 31;
      __fp16 __attribute__((ext_vector_type(2))) pk =
          __builtin_amdgcn_cvt_pkrtz(sout[row][c0], sout[row][c0 + 1]);
      dst[i] = *(const unsigned*)&pk;
    }
  }
}

// ---------------- Stage 2: per-pair MLP via 32x32x16 f16 MFMA ----------------
// Grid (2,32,32); block 256 = 4 waves; wave w owns chunks {2w,2w+1} of 32 g2.
// 8 iterations, each covering 2 g1 rows x 2 chunks = 4 independent MFMA
// chains + 4 independent epilogues. __launch_bounds__(256,2): 256-VGPR
// budget -> no spill (R9's (256,4) cap of 128 caused scratch-spill), and the
// scheduler can keep all 4 chains + next iteration's ds_reads in flight.
__global__ __launch_bounds__(256, 2) void mlp_pairs(
    const float* __restrict__ ws,
    const float* __restrict__ fc2_w, const float* __restrict__ fc2_b,
    const float* __restrict__ fc3_w, const float* __restrict__ fc3_b,
    float* __restrict__ out) {
  const int b = blockIdx.z;
  const int g1_0 = blockIdx.y * 16;
  const int g2_0 = blockIdx.x * 256;
  const int t = threadIdx.x;
  const int w = t >> 6, l = t & 63;
  const int col = l & 31;   // pair within chunk
  const int half = l >> 5;  // k-subrange / n-subset selector
  const int kb = half * 8;

  __shared__ __align__(16) unsigned short sPh[16 * 32];  // 1 KB P tile
  {
    const unsigned* Psrc = (const unsigned*)((const unsigned short*)ws + WS_P16H) +
                           ((size_t)b * G + g1_0) * 16;
    ((unsigned*)sPh)[t] = Psrc[t];
  }

  // A-frags: W2t[n=col][k = kb+j] (f16 RTN); k-halves [0,16) / [16,32)
  v8h A0, A1;
#pragma unroll
  for (int j = 0; j < 8; ++j) {
    A0[j] = (_Float16)fc2_w[(kb + j) * 32 + col];
    A1[j] = (_Float16)fc2_w[(16 + kb + j) * 32 + col];
  }
  // Bias as C-seed; fc3 weights as packed pairs (n-mapped)
  v16f biasC;
  F2x8 w3p;
#pragma unroll
  for (int r = 0; r < 16; ++r) {
    const int n = (r & 3) + 8 * (r >> 2) + 4 * half;
    biasC[r] = fc2_b[n];
    ((float*)&w3p)[r] = fc3_w[n];
  }
  const float b3 = fc3_b[0];

  // Q fragments (g1-invariant, fp16) for both chunks
  HQ qlo[2], qhi[2];
#pragma unroll
  for (int c = 0; c < 2; ++c) {
    const unsigned short* qp = (const unsigned short*)ws + WS_Q16H +
        ((size_t)b * G + g2_0 + (2 * w + c) * 32 + col) * 32;
    qlo[c] = __builtin_bit_cast(HQ, *(const uint4*)(qp + kb));
    qhi[c] = __builtin_bit_cast(HQ, *(const uint4*)(qp + 16 + kb));
  }
  __syncthreads();

  const f2v z2 = {0.f, 0.f};
  float* op = out + (((size_t)b * G + g1_0) * G) + g2_0 + w * 64 + half * 32 + col;
#pragma unroll
  for (int i = 0; i < 8; ++i) {
    const int ra = 2 * i, rb = 2 * i + 1;
    const HQ palo = __builtin_bit_cast(HQ, *(const uint4*)(sPh + ra * 32 + kb));
    const HQ pahi = __builtin_bit_cast(HQ, *(const uint4*)(sPh + ra * 32 + 16 + kb));
    const HQ pblo = __builtin_bit_cast(HQ, *(const uint4*)(sPh + rb * 32 + kb));
    const HQ pbhi = __builtin_bit_cast(HQ, *(const uint4*)(sPh + rb * 32 + 16 + kb));

    // 8 B-frags, 8 MFMAs: 4 independent chains
    const v8h Ba0lo = relu_add(palo, qlo[0]);
    const v8h Ba0hi = relu_add(pahi, qhi[0]);
    const v8h Ba1lo = relu_add(palo, qlo[1]);
    const v8h Ba1hi = relu_add(pahi, qhi[1]);
    const v8h Bb0lo = relu_add(pblo, qlo[0]);
    const v8h Bb0hi = relu_add(pbhi, qhi[0]);
    const v8h Bb1lo = relu_add(pblo, qlo[1]);
    const v8h Bb1hi = relu_add(pbhi, qhi[1]);

    v16f aa0 = __builtin_amdgcn_mfma_f32_32x32x16_f16(A0, Ba0lo, biasC, 0, 0, 0);
    v16f aa1 = __builtin_amdgcn_mfma_f32_32x32x16_f16(A0, Ba1lo, biasC, 0, 0, 0);
    v16f ab0 = __builtin_amdgcn_mfma_f32_32x32x16_f16(A0, Bb0lo, biasC, 0, 0, 0);
    v16f ab1 = __builtin_amdgcn_mfma_f32_32x32x16_f16(A0, Bb1lo, biasC, 0, 0, 0);
    aa0 = __builtin_amdgcn_mfma_f32_32x32x16_f16(A1, Ba0hi, aa0, 0, 0, 0);
    aa1 = __builtin_amdgcn_mfma_f32_32x32x16_f16(A1, Ba1hi, aa1, 0, 0, 0);
    ab0 = __builtin_amdgcn_mfma_f32_32x32x16_f16(A1, Bb0hi, ab0, 0, 0, 0);
    ab1 = __builtin_amdgcn_mfma_f32_32x32x16_f16(A1, Bb1hi, ab1, 0, 0, 0);

    // 4 packed-fp32 epilogues
    const F2x8 fa0 = __builtin_bit_cast(F2x8, aa0);
    const F2x8 fa1 = __builtin_bit_cast(F2x8, aa1);
    const F2x8 fb0 = __builtin_bit_cast(F2x8, ab0);
    const F2x8 fb1 = __builtin_bit_cast(F2x8, ab1);
    f2v ea0 = z2, ea1 = z2, eb0 = z2, eb1 = z2;
#pragma unroll
    for (int k = 0; k < 8; ++k) {
      ea0 = __builtin_elementwise_max(fa0.v[k], z2) * w3p.v[k] + ea0;
      ea1 = __builtin_elementwise_max(fa1.v[k], z2) * w3p.v[k] + ea1;
      eb0 = __builtin_elementwise_max(fb0.v[k], z2) * w3p.v[k] + eb0;
      eb1 = __builtin_elementwise_max(fb1.v[k], z2) * w3p.v[k] + eb1;
    }
    const float sa0 = ea0[0] + ea0[1], sa1 = ea1[0] + ea1[1];
    const float sb0 = eb0[0] + eb0[1], sb1 = eb1[0] + eb1[1];

    // single-shuffle cross-half reduce per row (select-swap)
    float ya = half ? sa1 : sa0;
    float za = half ? sa0 : sa1;
    ya += __shfl_xor(za, 32);
    float yb = half ? sb1 : sb0;
    float zb = half ? sb0 : sb1;
    yb += __shfl_xor(zb, 32);

    op[(size_t)ra * G] = ya + b3;
    op[(size_t)rb * G] = yb + b3;
  }
}

extern "C" void kernel_launch(void* const* d_in, const int* in_sizes, int n_in,
                              void* d_out, int out_size, void* d_ws, size_t ws_size,
                              hipStream_t stream) {
  const float* h     = (const float*)d_in[0];
  const int*   pp    = (const int*)d_in[1];
  const int*   pd    = (const int*)d_in[2];
  const int*   rec   = (const int*)d_in[3];
  const float* Wq1   = (const float*)d_in[4];
  const float* Wk1   = (const float*)d_in[5];
  const float* Wq2   = (const float*)d_in[6];
  const float* Wk2   = (const float*)d_in[7];
  const float* fc1_w = (const float*)d_in[8];
  const float* fc1_b = (const float*)d_in[9];
  const float* fc2_w = (const float*)d_in[10];
  const float* fc2_b = (const float*)d_in[11];
  const float* fc3_w = (const float*)d_in[12];
  const float* fc3_b = (const float*)d_in[13];
  float* out = (float*)d_out;
  float* ws  = (float*)d_ws;

  stage01<<<dim3(256), dim3(256), 0, stream>>>(
      h, pp, pd, rec, Wq1, Wk1, Wq2, Wk2, fc1_w, fc1_b, ws);
  mlp_pairs<<<dim3(2, 32, 32), dim3(256), 0, stream>>>(
      ws, fc2_w, fc2_b, fc3_w, fc3_b, out);
}

// Round 11
// 143.256 us; speedup vs baseline: 1.4778x; 1.0070x over previous
//
#include <hip/hip_runtime.h>

// Reinsertion: B=32, G=512, D=128, H=4, KD=32. Output (B,G,G) fp32.
//
// R11 = R10 + prologue attack on mlp_pairs:
//  - stage01 block 0 writes pre-swizzled tables into ws: W2^T f16 [col][k],
//    fc2_b / fc3_w in MFMA n-map order -> mlp prologue is ~13 vector loads
//    (was ~70 scalar gathers).
//  - g1 tile 16 -> 32 (grid (2,16,32), 1024 blocks): prologue amortized 2x.
//  - loop body / (256,2) VGPR budget / fp16 P,Q / select-swap store from R10.

#define B 32
#define G 512
#define D 128
#define NH 4
#define KD 32
#define NORMF 0.17677669529663687f  // 1/sqrt(32)

// ws layout:
//  bytes [0, 2048): W2^T f16, wt[col*32 + k]
//  floats [1024, 1056): fc2_b swizzled  bias_sw[half*16 + r] = fc2_b[n(r,half)]
//  floats [1056, 1088): fc3_w swizzled  w3_sw[half*16 + r]   = fc3_w[n(r,half)]
//  half-idx [131072, ...): P fp16 [(b*G+g)*32 + j]
//  half-idx [655360, ...): Q fp16
#define WS_BIASF 1024
#define WS_W3F   1056
#define WS_P16H  131072
#define WS_Q16H  655360

typedef float v16f __attribute__((ext_vector_type(16)));
typedef float f2v __attribute__((ext_vector_type(2)));
typedef _Float16 v8h __attribute__((ext_vector_type(8)));
typedef _Float16 h2v __attribute__((ext_vector_type(2)));

struct HQ { h2v h[4]; };   // 8 halves = 4 VGPRs
struct F2x8 { f2v v[8]; }; // 16 floats as 8 packed pairs

__device__ __forceinline__ v8h relu_add(const HQ& p, const HQ& q) {
  const h2v z = {(_Float16)0.0f, (_Float16)0.0f};
  HQ r;
#pragma unroll
  for (int i = 0; i < 4; ++i)
    r.h[i] = __builtin_elementwise_max(p.h[i] + q.h[i], z);
  return __builtin_bit_cast(v8h, r);
}

// ---------------- Stage 0+1 fused: A-tables (LDS) + P/Q + weight swizzle ----
__global__ __launch_bounds__(256) void stage01(
    const float* __restrict__ h, const int* __restrict__ pp,
    const int* __restrict__ pd, const int* __restrict__ rec,
    const float* __restrict__ Wq1, const float* __restrict__ Wk1,
    const float* __restrict__ Wq2, const float* __restrict__ Wk2,
    const float* __restrict__ fc1_w, const float* __restrict__ fc1_b,
    const float* __restrict__ fc2_w, const float* __restrict__ fc2_b,
    const float* __restrict__ fc3_w,
    float* __restrict__ ws) {
  const int bx = blockIdx.x;
  const int b = bx >> 3, g0 = (bx & 7) * 64;
  const int t = threadIdx.x;

  // Block 0: emit pre-swizzled stage-2 weight tables (tiny, once).
  if (bx == 0 && t < 32) {
    _Float16* wt = (_Float16*)ws;
#pragma unroll
    for (int k = 0; k < 32; ++k) wt[t * 32 + k] = (_Float16)fc2_w[k * 32 + t];
    const int r = t & 15, hf = t >> 4;
    const int n = (r & 3) + 8 * (r >> 2) + 4 * hf;
    ws[WS_BIASF + t] = fc2_b[n];
    ws[WS_W3F + t]   = fc3_w[n];
  }

  __shared__ float hp[D], hd[D];
  __shared__ float qq[4][NH * KD];   // q1p,q2p,q1d,q2d
  __shared__ float sA[4][NH][D];     // Apq,Apo,Adp,Ado
  __shared__ float sc[64][17];
  __shared__ float sout[64][33];

  if (t < 128) {
    hp[t] = h[((size_t)b * G + pp[b]) * D + t];
  } else {
    const int u = t - 128;
    hd[u] = h[((size_t)b * G + pd[b]) * D + u];
  }
  __syncthreads();

  if (t < 128) {  // t -> (head hh, key k); dot over d
    const int hh = t >> 5, k = t & 31;
    const float* wq1 = Wq1 + hh * D * KD + k;
    const float* wq2 = Wq2 + hh * D * KD + k;
    float s1p = 0.f, s2p = 0.f, s1d = 0.f, s2d = 0.f;
    for (int d = 0; d < D; ++d) {
      const float w1 = wq1[d * KD], w2 = wq2[d * KD];
      const float xp = hp[d], xd = hd[d];
      s1p = fmaf(xp, w1, s1p);
      s2p = fmaf(xp, w2, s2p);
      s1d = fmaf(xd, w1, s1d);
      s2d = fmaf(xd, w2, s2d);
    }
    qq[0][t] = s1p; qq[1][t] = s2p; qq[2][t] = s1d; qq[3][t] = s2d;
  }
  __syncthreads();

  {  // A[table][hh][d]; thread t: d = t&127, two heads
    const int d = t & 127;
    const int h0 = (t >> 7) * 2;
#pragma unroll
    for (int hh = h0; hh < h0 + 2; ++hh) {
      const float* wk1 = Wk1 + hh * D * KD + d * KD;
      const float* wk2 = Wk2 + hh * D * KD + d * KD;
      float apq = 0.f, apo = 0.f, adp = 0.f, ado = 0.f;
#pragma unroll
      for (int k = 0; k < KD; ++k) {
        const float w1 = wk1[k], w2 = wk2[k];
        apq = fmaf(qq[0][hh * 32 + k], w1, apq);
        adp = fmaf(qq[2][hh * 32 + k], w1, adp);
        apo = fmaf(qq[1][hh * 32 + k], w2, apo);
        ado = fmaf(qq[3][hh * 32 + k], w2, ado);
      }
      sA[0][hh][d] = NORMF * apq;
      sA[1][hh][d] = NORMF * apo;
      sA[2][hh][d] = NORMF * adp;
      sA[3][hh][d] = NORMF * ado;
    }
  }
  __syncthreads();

  // Phase B: compat dots + fc1 decomposition
  const int gl = t & 63;
  const int hh = __builtin_amdgcn_readfirstlane(t >> 6);  // wave id == head
  const int g = g0 + gl;
  const float4* hg4 = (const float4*)(h + ((size_t)b * G + g) * D);
  const float4* hn4 = (const float4*)(h + ((size_t)b * G + rec[b * G + g]) * D);

  float cpp = 0.f, cpo = 0.f, cdp = 0.f, cdo = 0.f;
#pragma unroll 4
  for (int d4 = 0; d4 < 32; ++d4) {
    const float4 x = hg4[d4], y = hn4[d4];
    const float4 a1 = *(const float4*)&sA[0][hh][4 * d4];
    const float4 a2 = *(const float4*)&sA[1][hh][4 * d4];
    const float4 a3 = *(const float4*)&sA[2][hh][4 * d4];
    const float4 a4 = *(const float4*)&sA[3][hh][4 * d4];
    cpp = fmaf(x.x, a1.x, fmaf(x.y, a1.y, fmaf(x.z, a1.z, fmaf(x.w, a1.w, cpp))));
    cpo = fmaf(y.x, a2.x, fmaf(y.y, a2.y, fmaf(y.z, a2.z, fmaf(y.w, a2.w, cpo))));
    cdp = fmaf(x.x, a3.x, fmaf(x.y, a3.y, fmaf(x.z, a3.z, fmaf(x.w, a3.w, cdp))));
    cdo = fmaf(y.x, a4.x, fmaf(y.y, a4.y, fmaf(y.z, a4.z, fmaf(y.w, a4.w, cdo))));
  }
  sc[gl][hh] = cpp; sc[gl][4 + hh] = cpo; sc[gl][8 + hh] = cdp; sc[gl][12 + hh] = cdo;
  __syncthreads();

  float u[16];
#pragma unroll
  for (int i = 0; i < 16; ++i) u[i] = sc[gl][i];

  float pv[8], qv[8];
#pragma unroll
  for (int jj = 0; jj < 8; ++jj) {
    const int j = hh * 8 + jj;  // wave-uniform -> s_load weights
    float p = 0.f, q = fc1_b[j];
#pragma unroll
    for (int i = 0; i < 8; ++i) {
      p = fmaf(u[i], fc1_w[i * 32 + j], p);
      q = fmaf(u[8 + i], fc1_w[(8 + i) * 32 + j], q);
    }
    pv[jj] = p; qv[jj] = q;
  }

  // pack to fp16, transpose via LDS, coalesced uint stores
#pragma unroll
  for (int jj = 0; jj < 8; ++jj) sout[gl][hh * 8 + jj] = pv[jj];
  __syncthreads();
  {
    unsigned* dst = (unsigned*)((unsigned short*)ws + WS_P16H) +
                    ((size_t)b * G + g0) * 16;
#pragma unroll
    for (int i = t; i < 1024; i += 256) {
      const int row = i >> 4, c0 = (2 * i) & 31;
      __fp16 __attribute__((ext_vector_type(2))) pk =
          __builtin_amdgcn_cvt_pkrtz(sout[row][c0], sout[row][c0 + 1]);
      dst[i] = *(const unsigned*)&pk;
    }
  }
  __syncthreads();
#pragma unroll
  for (int jj = 0; jj < 8; ++jj) sout[gl][hh * 8 + jj] = qv[jj];
  __syncthreads();
  {
    unsigned* dst = (unsigned*)((unsigned short*)ws + WS_Q16H) +
                    ((size_t)b * G + g0) * 16;
#pragma unroll
    for (int i = t; i < 1024; i += 256) {
      const int row = i >> 4, c0 = (2 * i) & 31;
      __fp16 __attribute__((ext_vector_type(2))) pk =
          __builtin_amdgcn_cvt_pkrtz(sout[row][c0], sout[row][c0 + 1]);
      dst[i] = *(const unsigned*)&pk;
    }
  }
}

// ---------------- Stage 2: per-pair MLP via 32x32x16 f16 MFMA ----------------
// Grid (2,16,32); block 256 = 4 waves; block tile 32 g1 x 256 g2; wave w owns
// chunks {2w,2w+1} of 32 g2. 16 iterations x (2 g1 rows x 2 chunks) = 4
// independent MFMA chains per iteration. Prologue: all operands from
// pre-swizzled ws tables via wide vector loads.
__global__ __launch_bounds__(256, 2) void mlp_pairs(
    const float* __restrict__ ws, const float* __restrict__ fc3_b,
    float* __restrict__ out) {
  const int b = blockIdx.z;
  const int g1_0 = blockIdx.y * 32;
  const int g2_0 = blockIdx.x * 256;
  const int t = threadIdx.x;
  const int w = t >> 6, l = t & 63;
  const int col = l & 31;   // pair within chunk
  const int half = l >> 5;  // k-subrange / n-subset selector
  const int kb = half * 8;

  __shared__ __align__(16) unsigned short sPh[32 * 32];  // 2 KB P tile
  {
    const unsigned* Psrc = (const unsigned*)((const unsigned short*)ws + WS_P16H) +
                           ((size_t)b * G + g1_0) * 16;
    ((unsigned*)sPh)[t] = Psrc[t];
    ((unsigned*)sPh)[t + 256] = Psrc[t + 256];
  }

  // A-frags from pre-swizzled W2^T f16 [col][k]: 2 x 16B loads
  const unsigned short* wt = (const unsigned short*)ws;
  const v8h A0 = __builtin_bit_cast(v8h, *(const uint4*)(wt + col * 32 + kb));
  const v8h A1 = __builtin_bit_cast(v8h, *(const uint4*)(wt + col * 32 + 16 + kb));
  // Bias / fc3 weights pre-swizzled in n-map order: 64B vector loads
  const v16f biasC = *(const v16f*)(ws + WS_BIASF + half * 16);
  const F2x8 w3p = __builtin_bit_cast(F2x8, *(const v16f*)(ws + WS_W3F + half * 16));
  const float b3 = fc3_b[0];

  // Q fragments (g1-invariant, fp16) for both chunks
  HQ qlo[2], qhi[2];
#pragma unroll
  for (int c = 0; c < 2; ++c) {
    const unsigned short* qp = (const unsigned short*)ws + WS_Q16H +
        ((size_t)b * G + g2_0 + (2 * w + c) * 32 + col) * 32;
    qlo[c] = __builtin_bit_cast(HQ, *(const uint4*)(qp + kb));
    qhi[c] = __builtin_bit_cast(HQ, *(const uint4*)(qp + 16 + kb));
  }
  __syncthreads();

  const f2v z2 = {0.f, 0.f};
  float* op = out + (((size_t)b * G + g1_0) * G) + g2_0 + w * 64 + half * 32 + col;
#pragma unroll
  for (int i = 0; i < 16; ++i) {
    const int ra = 2 * i, rb = 2 * i + 1;
    const HQ palo = __builtin_bit_cast(HQ, *(const uint4*)(sPh + ra * 32 + kb));
    const HQ pahi = __builtin_bit_cast(HQ, *(const uint4*)(sPh + ra * 32 + 16 + kb));
    const HQ pblo = __builtin_bit_cast(HQ, *(const uint4*)(sPh + rb * 32 + kb));
    const HQ pbhi = __builtin_bit_cast(HQ, *(const uint4*)(sPh + rb * 32 + 16 + kb));

    // 8 B-frags, 8 MFMAs: 4 independent chains
    const v8h Ba0lo = relu_add(palo, qlo[0]);
    const v8h Ba0hi = relu_add(pahi, qhi[0]);
    const v8h Ba1lo = relu_add(palo, qlo[1]);
    const v8h Ba1hi = relu_add(pahi, qhi[1]);
    const v8h Bb0lo = relu_add(pblo, qlo[0]);
    const v8h Bb0hi = relu_add(pbhi, qhi[0]);
    const v8h Bb1lo = relu_add(pblo, qlo[1]);
    const v8h Bb1hi = relu_add(pbhi, qhi[1]);

    v16f aa0 = __builtin_amdgcn_mfma_f32_32x32x16_f16(A0, Ba0lo, biasC, 0, 0, 0);
    v16f aa1 = __builtin_amdgcn_mfma_f32_32x32x16_f16(A0, Ba1lo, biasC, 0, 0, 0);
    v16f ab0 = __builtin_amdgcn_mfma_f32_32x32x16_f16(A0, Bb0lo, biasC, 0, 0, 0);
    v16f ab1 = __builtin_amdgcn_mfma_f32_32x32x16_f16(A0, Bb1lo, biasC, 0, 0, 0);
    aa0 = __builtin_amdgcn_mfma_f32_32x32x16_f16(A1, Ba0hi, aa0, 0, 0, 0);
    aa1 = __builtin_amdgcn_mfma_f32_32x32x16_f16(A1, Ba1hi, aa1, 0, 0, 0);
    ab0 = __builtin_amdgcn_mfma_f32_32x32x16_f16(A1, Bb0hi, ab0, 0, 0, 0);
    ab1 = __builtin_amdgcn_mfma_f32_32x32x16_f16(A1, Bb1hi, ab1, 0, 0, 0);

    // 4 packed-fp32 epilogues
    const F2x8 fa0 = __builtin_bit_cast(F2x8, aa0);
    const F2x8 fa1 = __builtin_bit_cast(F2x8, aa1);
    const F2x8 fb0 = __builtin_bit_cast(F2x8, ab0);
    const F2x8 fb1 = __builtin_bit_cast(F2x8, ab1);
    f2v ea0 = z2, ea1 = z2, eb0 = z2, eb1 = z2;
#pragma unroll
    for (int k = 0; k < 8; ++k) {
      ea0 = __builtin_elementwise_max(fa0.v[k], z2) * w3p.v[k] + ea0;
      ea1 = __builtin_elementwise_max(fa1.v[k], z2) * w3p.v[k] + ea1;
      eb0 = __builtin_elementwise_max(fb0.v[k], z2) * w3p.v[k] + eb0;
      eb1 = __builtin_elementwise_max(fb1.v[k], z2) * w3p.v[k] + eb1;
    }
    const float sa0 = ea0[0] + ea0[1], sa1 = ea1[0] + ea1[1];
    const float sb0 = eb0[0] + eb0[1], sb1 = eb1[0] + eb1[1];

    // single-shuffle cross-half reduce per row (select-swap)
    float ya = half ? sa1 : sa0;
    float za = half ? sa0 : sa1;
    ya += __shfl_xor(za, 32);
    float yb = half ? sb1 : sb0;
    float zb = half ? sb0 : sb1;
    yb += __shfl_xor(zb, 32);

    op[(size_t)ra * G] = ya + b3;
    op[(size_t)rb * G] = yb + b3;
  }
}

extern "C" void kernel_launch(void* const* d_in, const int* in_sizes, int n_in,
                              void* d_out, int out_size, void* d_ws, size_t ws_size,
                              hipStream_t stream) {
  const float* h     = (const float*)d_in[0];
  const int*   pp    = (const int*)d_in[1];
  const int*   pd    = (const int*)d_in[2];
  const int*   rec   = (const int*)d_in[3];
  const float* Wq1   = (const float*)d_in[4];
  const float* Wk1   = (const float*)d_in[5];
  const float* Wq2   = (const float*)d_in[6];
  const float* Wk2   = (const float*)d_in[7];
  const float* fc1_w = (const float*)d_in[8];
  const float* fc1_b = (const float*)d_in[9];
  const float* fc2_w = (const float*)d_in[10];
  const float* fc2_b = (const float*)d_in[11];
  const float* fc3_w = (const float*)d_in[12];
  const float* fc3_b = (const float*)d_in[13];
  float* out = (float*)d_out;
  float* ws  = (float*)d_ws;

  stage01<<<dim3(256), dim3(256), 0, stream>>>(
      h, pp, pd, rec, Wq1, Wk1, Wq2, Wk2, fc1_w, fc1_b, fc2_w, fc2_b, fc3_w, ws);
  mlp_pairs<<<dim3(2, 16, 32), dim3(256), 0, stream>>>(ws, fc3_b, out);
}